// Round 7
// baseline (1005.207 us; speedup 1.0000x reference)
//
#include <hip/hip_runtime.h>

// QLSTM: B=512, T=1024, IN=1, H=64.
// R7 = R5's split-K 8-wave structure (verified absmax 0.0) + R6's M=2
// weight-sharing + LDS-transposed weight staging.
//
// Six rounds of evidence: the 64 weights/lane will NOT stay VGPR-resident
// (VGPR 44/32/76/88 across pins/volatile/waves_per_eu), so weights are
// re-fetched from memory EVERY step. The only reducers that work:
//  - share each loaded quad across M=2 batch elements in the same wave
//    (halves traffic: 128 -> 64 KB/step/CU),
//  - serve them from LDS in TRANSPOSED-QUAD layout [q][l] so each read is
//    a contiguous conflict-free ds_read_b128 (the global path was 64-lane
//    scattered: lane l reads row l, stride 256 B = 64 lines/instruction),
//  - keep 2 waves/SIMD (R6's 1 wave/SIMD exposed all latency: 840us).
//
// Block = 512 threads = 8 waves: wave w -> gate (w&3), k-half (w>>2).
// Grid = 256 = 1 block/CU. Lane l owns hidden unit l.
//
// Sync (1 barrier/step), all patterns proven in R0/R5:
//  - partials exchanged via DOUBLE-BUFFERED part[t&1][8][64] (float2 packs
//    both elements); parity prevents WAR without a 2nd barrier.
//  - c,h update computed redundantly by all 8 waves for both elements.
//  - per-wave PRIVATE h copies hs[w][m][64]: same-wave DS write->read
//    ordering, no barrier.
// Numerics: gate sum = (bias + x*u + sum(k<32)) + sum(k>=32) -- exactly
// R5's order, which measured absmax 0.0.

#define TLEN 1024
#define HID  64

__device__ __forceinline__ float fast_sigmoid(float x) {
    return __builtin_amdgcn_rcpf(1.0f + __expf(-x));   // hw exp + hw rcp
}
__device__ __forceinline__ float fast_tanh(float x) {
    return __builtin_fmaf(2.0f, fast_sigmoid(2.0f * x), -1.0f);
}

__global__ __launch_bounds__(512, 2)
void qlstm_kernel(const float* __restrict__ x,      // [B, T, 1]
                  const float* __restrict__ W_ih,   // [256, 1]
                  const float* __restrict__ W_hh,   // [256, 64]
                  const float* __restrict__ b_ih,   // [256]
                  const float* __restrict__ b_hh,   // [256]
                  const float* __restrict__ W_lin,  // [1, 64]
                  const float* __restrict__ b_lin,  // [1]
                  float* __restrict__ out)          // [B]
{
    const int b0  = blockIdx.x * 2;     // two batch elements per block
    const int tid = threadIdx.x;
    const int w   = tid >> 6;           // wave 0..7
    const int g   = w & 3;              // gate i,f,g,o
    const int hf  = w >> 2;             // k-half: 0 -> k<32, 1 -> k>=32
    const int l   = tid & 63;           // hidden unit

    __shared__ __align__(16) float  xs[2][TLEN];       //  8 KB
    __shared__ __align__(16) float4 Wlds[8][8][HID];   // 64 KB transposed quads
    __shared__ __align__(16) float  hs[8][2][HID];     //  4 KB per-wave h copies
    __shared__ __align__(16) float2 part[2][8][HID];   //  8 KB dbuf partials
    // total ~84 KB -> 1 block/CU (grid is 256 = exactly 1 per CU)

    // Stage both x rows: 2048 floats / 512 threads = one float4 each.
    ((float4*)xs)[tid] = ((const float4*)(x + (size_t)b0 * TLEN))[tid];

    // Stage this wave's 8 KB weight slice, TRANSPOSED to [q][l]:
    // Wlds[w][q][l] = W_hh[g*64+l][32*hf + 4q .. +4). Read once (scattered,
    // amortized over 1024 steps); per-step reads become contiguous b128.
    const int row = g * HID + l;
    {
        const float4* Wr = (const float4*)(W_hh + (size_t)row * HID + 32 * hf);
        #pragma unroll
        for (int q = 0; q < 8; ++q) Wlds[w][q][l] = Wr[q];
    }

    const float u    = W_ih[row];                 // IN == 1
    const float bias = b_ih[row] + b_hh[row];
    const float wlin = W_lin[l];

    float c0 = 0.0f, h0 = 0.0f, c1 = 0.0f, h1 = 0.0f;
    hs[w][0][l] = 0.0f;
    hs[w][1][l] = 0.0f;
    __syncthreads();   // xs + Wlds + hs ready

    const float4* wp  = &Wlds[w][0][l];      // stride 64 float4 per q (ds offset imm)
    const float*  h0p = &hs[w][0][32 * hf];  // this wave's k-half, element 0
    const float*  h1p = &hs[w][1][32 * hf];  // element 1

    for (int t = 0; t < TLEN; ++t) {
        const int p = t & 1;

        // Partial dot over this wave's k-half, BOTH elements sharing each
        // weight quad. Half 0 seeds bias + x*u (preserves R5's exact order).
        float acc0, acc1;
        if (hf == 0) {
            acc0 = __builtin_fmaf(xs[0][t], u, bias);
            acc1 = __builtin_fmaf(xs[1][t], u, bias);
        } else {
            acc0 = 0.0f; acc1 = 0.0f;
        }
        #pragma unroll
        for (int q = 0; q < 8; ++q) {
            const float4 wv  = wp[(size_t)q * HID];          // ds_read_b128, contiguous
            const float4 hk0 = *(const float4*)&h0p[4 * q];  // same-addr broadcast
            const float4 hk1 = *(const float4*)&h1p[4 * q];
            acc0 = __builtin_fmaf(hk0.x, wv.x, acc0);
            acc1 = __builtin_fmaf(hk1.x, wv.x, acc1);
            acc0 = __builtin_fmaf(hk0.y, wv.y, acc0);
            acc1 = __builtin_fmaf(hk1.y, wv.y, acc1);
            acc0 = __builtin_fmaf(hk0.z, wv.z, acc0);
            acc1 = __builtin_fmaf(hk1.z, wv.z, acc1);
            acc0 = __builtin_fmaf(hk0.w, wv.w, acc0);
            acc1 = __builtin_fmaf(hk1.w, wv.w, acc1);
        }
        part[p][w][l] = make_float2(acc0, acc1);  // one ds_write_b64, conflict-free
        __syncthreads();                          // the ONE barrier per step

        // Redundant tail in all 8 waves: gate sums (half0 + half1), both elems.
        const float2 q0a = part[p][0][l], q0b = part[p][4][l];  // gate i
        const float2 q1a = part[p][1][l], q1b = part[p][5][l];  // gate f
        const float2 q2a = part[p][2][l], q2b = part[p][6][l];  // gate g
        const float2 q3a = part[p][3][l], q3b = part[p][7][l];  // gate o
        {   // element 0
            const float ai = fast_sigmoid(q0a.x + q0b.x);
            const float af = fast_sigmoid(q1a.x + q1b.x);
            const float ag = fast_tanh   (q2a.x + q2b.x);
            const float ao = fast_sigmoid(q3a.x + q3b.x);
            c0 = __builtin_fmaf(af, c0, ai * ag);
            h0 = ao * fast_tanh(c0);
            hs[w][0][l] = h0;                     // private copy; no barrier
        }
        {   // element 1
            const float ai = fast_sigmoid(q0a.y + q0b.y);
            const float af = fast_sigmoid(q1a.y + q1b.y);
            const float ag = fast_tanh   (q2a.y + q2b.y);
            const float ao = fast_sigmoid(q3a.y + q3b.y);
            c1 = __builtin_fmaf(af, c1, ai * ag);
            h1 = ao * fast_tanh(c1);
            hs[w][1][l] = h1;                     // private copy; no barrier
        }
    }

    // out[b0+m] = dot(h_m, W_lin) + b_lin : wave 0 -> m=0, wave 1 -> m=1.
    if (w == 0 || w == 1) {
        float v = ((w == 0) ? h0 : h1) * wlin;
        #pragma unroll
        for (int off = 32; off > 0; off >>= 1)
            v += __shfl_down(v, off, 64);
        if (l == 0) out[b0 + w] = v + b_lin[0];
    }
}

extern "C" void kernel_launch(void* const* d_in, const int* in_sizes, int n_in,
                              void* d_out, int out_size, void* d_ws, size_t ws_size,
                              hipStream_t stream) {
    const float* x     = (const float*)d_in[0];
    const float* W_ih  = (const float*)d_in[1];
    const float* W_hh  = (const float*)d_in[2];
    const float* b_ih  = (const float*)d_in[3];
    const float* b_hh  = (const float*)d_in[4];
    const float* W_lin = (const float*)d_in[5];
    const float* b_lin = (const float*)d_in[6];
    float* out = (float*)d_out;

    const int B = out_size;  // 512
    qlstm_kernel<<<B / 2, 512, 0, stream>>>(x, W_ih, W_hh, b_ih, b_hh, W_lin, b_lin, out);
}

// Round 8
// 772.838 us; speedup vs baseline: 1.3007x; 1.3007x over previous
//
#include <hip/hip_runtime.h>

// QLSTM: B=512, T=1024, IN=1, H=64.
// R8 = R0's verified skeleton (4 waves/elem, grid 512, 2 blocks/CU, ONE
// barrier/step -- every departure from it regressed: R5 +24%, R6 +43%,
// R7 +72%) with two in-place fixes for R0's measured per-step costs:
//
// 1) WEIGHT SUPPLY SPLIT: weights can't be kept in VGPRs (proven R0-R4:
//    allocator caps at 44-88 regs and re-fetches every step). R0 streamed
//    all 128 KB/step/CU through L1 (~1355 cyc, the measured step time).
//    Now quads 0-7 are served per-step from LDS (transposed [w][q][l]
//    layout -> contiguous conflict-free ds_read_b128) while quads 8-15
//    stay on the global/L1 path. Two pipes in parallel: ~675 cyc L1 +
//    ~512 cyc LDS instead of ~1355 cyc on one pipe.
//
// 2) h BROADCAST VIA READLANE: R0 bounced h through LDS (write + 16
//    broadcast reads/step); at VGPR=44 the scheduler couldn't hoist the
//    reads -> repeated ~120cy exposed LDS latency inside the serial chain.
//    Each wave computes h redundantly in a register, so h[k] is available
//    as readlane(h,k) (uniform -> SGPR operand). Deletes the h LDS
//    round-trip; identical values, identical FMA order (absmax 0.0).
//
// Sync unchanged: gate activations exchanged via DOUBLE-BUFFERED
// act[t&1][4][64] (parity prevents WAR), ONE __syncthreads per step;
// c,h update computed redundantly by all 4 waves.

#define TLEN 1024
#define HID  64

__device__ __forceinline__ float fast_sigmoid(float x) {
    return __builtin_amdgcn_rcpf(1.0f + __expf(-x));   // hw exp + hw rcp
}
__device__ __forceinline__ float fast_tanh(float x) {
    return __builtin_fmaf(2.0f, fast_sigmoid(2.0f * x), -1.0f);
}

__device__ __forceinline__ float lane_bcast(float v, int k) {
    // h[k] broadcast: uniform result lands in an SGPR (free VALU operand).
    return __int_as_float(__builtin_amdgcn_readlane(__float_as_int(v), k));
}

__global__ __launch_bounds__(256, 2)
void qlstm_kernel(const float* __restrict__ x,      // [B, T, 1]
                  const float* __restrict__ W_ih,   // [256, 1]
                  const float* __restrict__ W_hh,   // [256, 64]
                  const float* __restrict__ b_ih,   // [256]
                  const float* __restrict__ b_hh,   // [256]
                  const float* __restrict__ W_lin,  // [1, 64]
                  const float* __restrict__ b_lin,  // [1]
                  float* __restrict__ out)          // [B]
{
    const int b   = blockIdx.x;
    const int tid = threadIdx.x;
    const int w   = tid >> 6;   // wave id == gate id (i,f,g,o)
    const int l   = tid & 63;   // hidden unit

    __shared__ __align__(16) float  xs[TLEN];          //  4 KB
    __shared__ __align__(16) float4 Wlds[4][8][HID];   // 32 KB: quads 0-7, transposed
    __shared__ __align__(16) float  act[2][4][HID];    //  2 KB: dbuf gate acts
    // total ~38.9 KB -> still 2 blocks/CU (<= 80 KB)

    // Stage this batch element's x row: 1024 floats, one float4 per thread.
    ((float4*)xs)[tid] = ((const float4*)(x + (size_t)b * TLEN))[tid];

    // Stage LOW-half weights (k<32) transposed: Wlds[w][q][l] = W_hh[row][4q..4q+4).
    // Per-step reads are then contiguous 16B/lane = conflict-free b128.
    const int row = w * HID + l;
    const float4* Wr = (const float4*)(W_hh + (size_t)row * HID);
    #pragma unroll
    for (int q = 0; q < 8; ++q) Wlds[w][q][l] = Wr[q];

    const float u    = W_ih[row];                 // IN == 1
    const float bias = b_ih[row] + b_hh[row];
    const float wlin = W_lin[l];

    float c = 0.0f, h = 0.0f;
    __syncthreads();   // xs + Wlds ready

    const float4* Wq = &Wlds[w][0][l];   // stride HID float4 per quad

    for (int t = 0; t < TLEN; ++t) {
        const int p = t & 1;
        const float xt = xs[t];                   // same-address broadcast

        // acc = W_hh[row,:] . h  + x_t*u + bias.
        // h[k] via readlane (no LDS); weights: q<8 from LDS, q>=8 from L1.
        // FMA order identical to the verified 586us kernel.
        float acc = __builtin_fmaf(xt, u, bias);
        #pragma unroll
        for (int q = 0; q < 8; ++q) {
            const float4 wv = Wq[(size_t)q * HID];        // ds_read_b128
            acc = __builtin_fmaf(lane_bcast(h, 4 * q + 0), wv.x, acc);
            acc = __builtin_fmaf(lane_bcast(h, 4 * q + 1), wv.y, acc);
            acc = __builtin_fmaf(lane_bcast(h, 4 * q + 2), wv.z, acc);
            acc = __builtin_fmaf(lane_bcast(h, 4 * q + 3), wv.w, acc);
        }
        #pragma unroll
        for (int q = 8; q < 16; ++q) {
            const float4 wv = Wr[q];                      // global (L1 stream)
            acc = __builtin_fmaf(lane_bcast(h, 4 * q + 0), wv.x, acc);
            acc = __builtin_fmaf(lane_bcast(h, 4 * q + 1), wv.y, acc);
            acc = __builtin_fmaf(lane_bcast(h, 4 * q + 2), wv.z, acc);
            acc = __builtin_fmaf(lane_bcast(h, 4 * q + 3), wv.w, acc);
        }

        // This wave's activation (wave-uniform branch).
        const float a = (w == 2) ? fast_tanh(acc) : fast_sigmoid(acc);
        act[p][w][l] = a;                         // stride-1, conflict-free
        __syncthreads();                          // the ONE barrier per step

        // Redundant elementwise update in every wave (keeps h per-wave-local).
        const float ai = act[p][0][l];
        const float af = act[p][1][l];
        const float ag = act[p][2][l];
        const float ao = act[p][3][l];
        c = __builtin_fmaf(af, c, ai * ag);
        h = ao * fast_tanh(c);
    }

    // out[b] = dot(h, W_lin) + b_lin  (wave 0 only)
    if (w == 0) {
        float v = h * wlin;
        #pragma unroll
        for (int off = 32; off > 0; off >>= 1)
            v += __shfl_down(v, off, 64);
        if (l == 0) out[b] = v + b_lin[0];
    }
}

extern "C" void kernel_launch(void* const* d_in, const int* in_sizes, int n_in,
                              void* d_out, int out_size, void* d_ws, size_t ws_size,
                              hipStream_t stream) {
    const float* x     = (const float*)d_in[0];
    const float* W_ih  = (const float*)d_in[1];
    const float* W_hh  = (const float*)d_in[2];
    const float* b_ih  = (const float*)d_in[3];
    const float* b_hh  = (const float*)d_in[4];
    const float* W_lin = (const float*)d_in[5];
    const float* b_lin = (const float*)d_in[6];
    float* out = (float*)d_out;

    const int B = out_size;  // 512
    qlstm_kernel<<<B, 256, 0, stream>>>(x, W_ih, W_hh, b_ih, b_hh, W_lin, b_lin, out);
}

// Round 9
// 651.568 us; speedup vs baseline: 1.5428x; 1.1861x over previous
//
#include <hip/hip_runtime.h>

// QLSTM: B=512, T=1024, IN=1, H=64.
// R9 = R0's verified 586us skeleton EXACTLY (4 waves/elem = gate/wave,
// grid 512, 2 blocks/CU, ONE barrier/step, LDS h-broadcast + dbuf act
// exchange) + ONE change: the weight supply is split across two pipes.
//
// Supply arithmetic (9 builds of evidence): weights will not stay in VGPRs
// (allocator caps at 44-88 regs); each CU re-streams 2 elem x 64 KB =
// 128 KB/step through ONE ~128 B/cyc pipe (L1 in R0, LDS in R7 -- same
// ~1000-1350 cyc either way; R0's measured step is 1355 cyc). Fix: serve
// quads 0-7 from LDS (staged once, TRANSPOSED [w][q][l] so lane l's 16B is
// contiguous -> conflict-free ds_read_b128) and quads 8-15 from L1 as in
// R0. 64 KB on each pipe, running CONCURRENTLY: ~512 cyc LDS || ~690 cyc L1.
//
// R8's readlane h-broadcast is REVERTED (it cost +540 issue cyc/SIMD/step:
// readlane+hazard-nops+movs); h goes back through the per-wave private LDS
// copy (same-wave DS write->read ordering, no barrier) as in R0.
//
// The unified unrolled dot loop constant-folds the per-quad source select,
// so the FMA ORDER IS BIT-IDENTICAL to the verified kernel (absmax 0.0).

#define TLEN 1024
#define HID  64

__device__ __forceinline__ float fast_sigmoid(float x) {
    return __builtin_amdgcn_rcpf(1.0f + __expf(-x));   // hw exp + hw rcp
}
__device__ __forceinline__ float fast_tanh(float x) {
    return __builtin_fmaf(2.0f, fast_sigmoid(2.0f * x), -1.0f);
}

__global__ __launch_bounds__(256, 2)
void qlstm_kernel(const float* __restrict__ x,      // [B, T, 1]
                  const float* __restrict__ W_ih,   // [256, 1]
                  const float* __restrict__ W_hh,   // [256, 64]
                  const float* __restrict__ b_ih,   // [256]
                  const float* __restrict__ b_hh,   // [256]
                  const float* __restrict__ W_lin,  // [1, 64]
                  const float* __restrict__ b_lin,  // [1]
                  float* __restrict__ out)          // [B]
{
    const int b   = blockIdx.x;
    const int tid = threadIdx.x;
    const int w   = tid >> 6;   // wave id == gate id (i,f,g,o)
    const int l   = tid & 63;   // hidden unit

    __shared__ __align__(16) float  xs[TLEN];          //  4 KB
    __shared__ __align__(16) float4 Wlds[4][8][HID];   // 32 KB: quads 0-7, transposed
    __shared__ __align__(16) float  hs4[4][HID];       //  1 KB: per-wave private h
    __shared__ __align__(16) float  act[2][4][HID];    //  2 KB: dbuf gate acts
    // ~39 KB/block -> 2 blocks/CU preserved (78 KB of 160 KB)

    // Stage this batch element's x row: 1024 floats, one float4 per thread.
    ((float4*)xs)[tid] = ((const float4*)(x + (size_t)b * TLEN))[tid];

    // Stage LOW-half weights transposed: Wlds[w][q][l] = W_hh[row][4q..4q+4).
    // One-time scattered read, amortized over 1024 steps; per-step reads are
    // contiguous 16B/lane b128, conflict-free.
    const int row = w * HID + l;
    const float4* Wr = (const float4*)(W_hh + (size_t)row * HID);
    #pragma unroll
    for (int q = 0; q < 8; ++q) Wlds[w][q][l] = Wr[q];

    const float u    = W_ih[row];                 // IN == 1
    const float bias = b_ih[row] + b_hh[row];
    const float wlin = W_lin[l];

    float c = 0.0f, h = 0.0f;
    hs4[w][l] = 0.0f;
    __syncthreads();   // xs + Wlds + hs4 ready

    const float4* Wq  = &Wlds[w][0][l];   // stride HID float4 per quad (imm offsets)
    const float*  hsw = hs4[w];

    for (int t = 0; t < TLEN; ++t) {
        const int p = t & 1;
        const float xt = xs[t];                   // same-address broadcast

        // acc = W_hh[row,:] . h + x_t*u + bias.  h from private LDS copy
        // (broadcast reads); weights q<8 from LDS slab, q>=8 from L1.
        // Source select folds at compile time -> FMA order == R0.
        float acc = __builtin_fmaf(xt, u, bias);
        #pragma unroll
        for (int q = 0; q < 16; ++q) {
            const float4 wv = (q < 8) ? Wq[(size_t)q * HID]   // ds_read_b128
                                      : Wr[q];                // global/L1 stream
            const float4 hk = *(const float4*)&hsw[4 * q];    // b32x4 broadcast
            acc = __builtin_fmaf(hk.x, wv.x, acc);
            acc = __builtin_fmaf(hk.y, wv.y, acc);
            acc = __builtin_fmaf(hk.z, wv.z, acc);
            acc = __builtin_fmaf(hk.w, wv.w, acc);
        }

        // This wave's activation (wave-uniform branch).
        const float a = (w == 2) ? fast_tanh(acc) : fast_sigmoid(acc);
        act[p][w][l] = a;                         // stride-1, conflict-free
        __syncthreads();                          // the ONE barrier per step

        // Redundant elementwise update in every wave.
        const float ai = act[p][0][l];
        const float af = act[p][1][l];
        const float ag = act[p][2][l];
        const float ao = act[p][3][l];
        c = __builtin_fmaf(af, c, ai * ag);
        h = ao * fast_tanh(c);
        hs4[w][l] = h;                            // private copy; no barrier
    }

    // out[b] = dot(h, W_lin) + b_lin  (wave 0 only)
    if (w == 0) {
        float v = h * wlin;
        #pragma unroll
        for (int off = 32; off > 0; off >>= 1)
            v += __shfl_down(v, off, 64);
        if (l == 0) out[b] = v + b_lin[0];
    }
}

extern "C" void kernel_launch(void* const* d_in, const int* in_sizes, int n_in,
                              void* d_out, int out_size, void* d_ws, size_t ws_size,
                              hipStream_t stream) {
    const float* x     = (const float*)d_in[0];
    const float* W_ih  = (const float*)d_in[1];
    const float* W_hh  = (const float*)d_in[2];
    const float* b_ih  = (const float*)d_in[3];
    const float* b_hh  = (const float*)d_in[4];
    const float* W_lin = (const float*)d_in[5];
    const float* b_lin = (const float*)d_in[6];
    float* out = (float*)d_out;

    const int B = out_size;  // 512
    qlstm_kernel<<<B, 256, 0, stream>>>(x, W_ih, W_hh, b_ih, b_hh, W_lin, b_lin, out);
}